// Round 6
// baseline (134.334 us; speedup 1.0000x reference)
//
#include <hip/hip_runtime.h>
#include <math.h>

#define B_   4
#define K_   200
#define DIM_ 256
#define T_   800

#define S_UP 68   // prep reduce-scratch stride
#define S_O  68   // main partial-row stride (16B-aligned)

__device__ __forceinline__ float silu_f(float x) {
    return x / (1.0f + __expf(-x));
}

// ---------------------------------------------------------------------------
// Prep: conv + scan + const folding. 16 tokens/block (4 passes, wave=token),
// wave-private LDS reduce (no intra-pass barriers). Grid (13, B_), 256 thr.
// cw[b][j][k]: j=0 beta0, j=1 beta1, j=2..17 B_j  (SoA, k-fastest).
// ---------------------------------------------------------------------------
__global__ __launch_bounds__(256) void prep_kernel(
        const float* __restrict__ dur,
        const float* __restrict__ feats,
        const float* __restrict__ c1w, const float* __restrict__ c1b,
        const float* __restrict__ c2w, const float* __restrict__ c2b,
        const float* __restrict__ sw1_w1, const float* __restrict__ sw1_b1,
        const float* __restrict__ sw2_w1, const float* __restrict__ sw2_b1,
        float* __restrict__ cw) {
    const int b = blockIdx.y, k0 = blockIdx.x * 16;
    const int tid = threadIdx.x, w = tid >> 6, l = tid & 63;

    __shared__ float wT[16][772];      // wT[oc][tap*256+c] (oc>=8 -> conv2)
    __shared__ float red[64][S_UP];    // wave w owns rows w*16..w*16+15
    __shared__ float sSc[K_], sEc[K_];
    __shared__ float sfeat[16][16];    // conv outputs (post-silu)

    // stage transposed conv weights (coalesced)
    for (int i = tid; i < 3 * DIM_ * 8; i += 256) {
        int tc = i >> 3, o = i & 7;
        wT[o][tc]     = c1w[i];
        wT[8 + o][tc] = c2w[i];
    }
    // wave 0: inclusive scan of 200 durations
    if (tid < 64) {
        float4 dv = make_float4(0.f, 0.f, 0.f, 0.f);
        if (tid < 50) dv = *(const float4*)&dur[b * K_ + tid * 4];
        float s0 = dv.x, s1 = s0 + dv.y, s2 = s1 + dv.z, s3 = s2 + dv.w;
        float sc = s3;
#pragma unroll
        for (int off = 1; off < 64; off <<= 1) {
            float v = __shfl_up(sc, off);
            if (tid >= off) sc += v;
        }
        float excl = sc - s3;
        if (tid < 50) {
            *(float4*)&sSc[tid * 4] = make_float4(excl, excl + s0, excl + s1, excl + s2);
            *(float4*)&sEc[tid * 4] = make_float4(excl + s0, excl + s1, excl + s2, excl + s3);
        }
    }
    __syncthreads();

    // 4 conv passes; wave w handles token k0 + pass*4 + w
    const float4* f4 = (const float4*)feats;
#pragma unroll
    for (int pass = 0; pass < 4; ++pass) {
        const int tk = pass * 4 + w;       // block-local token index
        const int k  = k0 + tk;
        float4 fv[3];
#pragma unroll
        for (int tap = 0; tap < 3; ++tap) {
            int kk = k - 1 + tap;
            bool valid = (kk >= 0 && kk < K_);
            int kc = valid ? kk : 0;
            float4 v = f4[(size_t)(b * K_ + kc) * 64 + l];
            fv[tap] = valid ? v : make_float4(0.f, 0.f, 0.f, 0.f);
        }
        float acc[16];
#pragma unroll
        for (int oc = 0; oc < 16; ++oc) acc[oc] = 0.f;
#pragma unroll
        for (int tap = 0; tap < 3; ++tap) {
#pragma unroll
            for (int oc = 0; oc < 16; ++oc) {
                float4 wv = *(const float4*)&wT[oc][tap * DIM_ + 4 * l];
                acc[oc] += fv[tap].x * wv.x + fv[tap].y * wv.y
                         + fv[tap].z * wv.z + fv[tap].w * wv.w;
            }
        }
#pragma unroll
        for (int oc = 0; oc < 16; ++oc) red[w * 16 + oc][l] = acc[oc];
        // wave-local transpose reduce (same-wave DS ordering; no barrier)
        {
            const int oc = (l >> 2) & 15, rq = l & 3;
            const float* base = &red[w * 16 + oc][rq * 16];
            float4 b0 = *(const float4*)&base[0];
            float4 b1 = *(const float4*)&base[4];
            float4 b2 = *(const float4*)&base[8];
            float4 b3 = *(const float4*)&base[12];
            float s = b0.x + b0.y + b0.z + b0.w + b1.x + b1.y + b1.z + b1.w
                    + b2.x + b2.y + b2.z + b2.w + b3.x + b3.y + b3.z + b3.w;
            s += __shfl_down(s, 1);
            s += __shfl_down(s, 2);
            if (rq == 0) {
                float bias = (oc < 8) ? c1b[oc] : c2b[oc & 7];
                sfeat[tk][oc] = silu_f(s + bias);
            }
        }
    }
    __syncthreads();

    // consts: B_j (16 tokens x 16 j = 256 threads)
    {
        const int tk = tid >> 4, j = tid & 15, kk = k0 + tk;
        if (kk < K_) {
            float st = sSc[kk], en = sEc[kk];
            float a = sw1_b1[j] - st * sw1_w1[j] + en * sw1_w1[16 + j];
#pragma unroll
            for (int i = 0; i < 8; ++i) a += sfeat[tk][i] * sw1_w1[(2 + i) * 16 + j];
            cw[(b * 18 + 2 + j) * K_ + kk] = a;
        }
    }
    // betas (32 threads)
    if (tid < 32) {
        const int which = tid >> 4, tk = tid & 15, kk = k0 + tk;
        if (kk < K_) {
            float st = sSc[kk], en = sEc[kk];
            float a = sw2_b1[which] - st * sw2_w1[which] + en * sw2_w1[2 + which];
#pragma unroll
            for (int i = 0; i < 8; ++i) a += sfeat[tk][8 + i] * sw2_w1[(2 + i) * 2 + which];
            cw[(b * 18 + which) * K_ + kk] = a;
        }
    }
}

// ---------------------------------------------------------------------------
// Main (R4 version — measured best): 4 frames/block (wave w <-> frame t0+w),
// grid (T/4, B), 256 thr. Consts straight from L2; 3 barriers total.
// ---------------------------------------------------------------------------
__global__ __launch_bounds__(256, 3) void main_kernel(
        const float* __restrict__ feats,
        const float* __restrict__ cw,
        const float* __restrict__ sw1_w1, const float* __restrict__ sw1_w2,
        const float* __restrict__ sw1_b2,
        const float* __restrict__ sw2_w1, const float* __restrict__ sw2_w2,
        const float* __restrict__ sw2_b2,
        const float* __restrict__ p1_w,   const float* __restrict__ p1_b,
        const float* __restrict__ p2_w,   const float* __restrict__ p2_b,
        float* __restrict__ out) {
    const int t0 = blockIdx.x * 4, b = blockIdx.y;
    const int tid = threadIdx.x, w = tid >> 6, l = tid & 63;
    const int t = t0 + w;

    __shared__ alignas(16) float upool[128 * S_O];  // rows 0..63 A-partials, 64..127 O-partials
    __shared__ alignas(16) float W4[K_][4];
    __shared__ alignas(16) float At[16][4];
    __shared__ float lw2T[16][16];
    __shared__ float lb2s[16];

    lw2T[tid & 15][tid >> 4] = sw1_w2[tid];
    if (tid < 16) lb2s[tid] = sw1_b2[tid];

    // ---- issue all const loads (coalesced, L2) ----
    const float* cbg = cw + b * 18 * K_;
    int kc[4];
#pragma unroll
    for (int i = 0; i < 4; ++i) { int k = l + 64 * i; kc[i] = (k < K_) ? k : (K_ - 1); }
    float Bv[4][16];
#pragma unroll
    for (int j = 0; j < 16; ++j)
#pragma unroll
        for (int i = 0; i < 4; ++i) Bv[i][j] = cbg[(2 + j) * K_ + kc[i]];
    float c0[4], c1[4];
#pragma unroll
    for (int i = 0; i < 4; ++i) { c0[i] = cbg[kc[i]]; c1[i] = cbg[K_ + kc[i]]; }

    __syncthreads();   // barrier 0: lw2T staged

    const float tf = (float)t;
    const float a0 = sw2_w1[0] - sw2_w1[2], a1 = sw2_w1[1] - sw2_w1[3];
    const float rw20 = sw2_w2[0], rw21 = sw2_w2[1], rw22 = sw2_w2[2], rw23 = sw2_w2[3];
    const float rb20 = sw2_b2[0], rb21 = sw2_b2[1];
    const float p10 = p1_w[0], p11 = p1_w[1], p1b0 = p1_b[0];

    // ---- phase 1: logits + wave softmax ----
    float lg[4];
#pragma unroll
    for (int i = 0; i < 4; ++i) {
        float h0 = silu_f(fmaf(a0, tf, c0[i]));
        float h1 = silu_f(fmaf(a1, tf, c1[i]));
        float g0 = silu_f(rb20 + h0 * rw20 + h1 * rw22);
        float g1 = silu_f(rb21 + h0 * rw21 + h1 * rw23);
        lg[i] = (l + 64 * i < K_) ? (g0 * p10 + g1 * p11 + p1b0) : -1e30f;
    }
    float m = fmaxf(fmaxf(lg[0], lg[1]), fmaxf(lg[2], lg[3]));
#pragma unroll
    for (int off = 32; off > 0; off >>= 1) m = fmaxf(m, __shfl_xor(m, off));
    float e0 = __expf(lg[0] - m), e1 = __expf(lg[1] - m);
    float e2 = __expf(lg[2] - m), e3 = __expf(lg[3] - m);
    float ssum = e0 + e1 + e2 + e3;
#pragma unroll
    for (int off = 32; off > 0; off >>= 1) ssum += __shfl_xor(ssum, off);
    float inv = 1.0f / ssum;
    float wgt[4] = { e0 * inv, e1 * inv, e2 * inv, e3 * inv };
#pragma unroll
    for (int i = 0; i < 4; ++i) { int k = l + 64 * i; if (k < K_) W4[k][w] = wgt[i]; }

    // ---- prefetch first 8 phase-3 feats tiles ----
    const int kb = w * 50;
    const float4* fB4 = (const float4*)(feats + (size_t)b * K_ * DIM_);
    float4 pf[8];
#pragma unroll
    for (int q = 0; q < 8; ++q) pf[q] = fB4[(size_t)(kb + q) * 64 + l];

    // ---- phase 2 ----
    float ajt[16];
#pragma unroll
    for (int j = 0; j < 16; ++j) ajt[j] = (sw1_w1[j] - sw1_w1[16 + j]) * tf;
    float hmat[4][16];
#pragma unroll
    for (int j = 0; j < 16; ++j)
#pragma unroll
        for (int i = 0; i < 4; ++i) hmat[i][j] = silu_f(ajt[j] + Bv[i][j]);
    float acc[16];
#pragma unroll
    for (int j = 0; j < 16; ++j) {
        float4 w0 = *(const float4*)&lw2T[j][0];
        float4 w1v = *(const float4*)&lw2T[j][4];
        float4 w2v = *(const float4*)&lw2T[j][8];
        float4 w3v = *(const float4*)&lw2T[j][12];
        float bj = lb2s[j];
        float s = 0.f;
#pragma unroll
        for (int i = 0; i < 4; ++i) {
            float c = bj
                + hmat[i][0]  * w0.x  + hmat[i][1]  * w0.y  + hmat[i][2]  * w0.z  + hmat[i][3]  * w0.w
                + hmat[i][4]  * w1v.x + hmat[i][5]  * w1v.y + hmat[i][6]  * w1v.z + hmat[i][7]  * w1v.w
                + hmat[i][8]  * w2v.x + hmat[i][9]  * w2v.y + hmat[i][10] * w2v.z + hmat[i][11] * w2v.w
                + hmat[i][12] * w3v.x + hmat[i][13] * w3v.y + hmat[i][14] * w3v.z + hmat[i][15] * w3v.w;
            s += wgt[i] * silu_f(c);
        }
        acc[j] = s;
    }
#pragma unroll
    for (int j = 0; j < 16; ++j) upool[(w * 16 + j) * S_O + l] = acc[j];

    __syncthreads();   // barrier 1: A-partials + W4 visible

    // ---- A transpose-reduce ----
    {
        const int rwv = tid >> 6, rj = (tid >> 2) & 15, rq = tid & 3;
        const float* base = &upool[(rwv * 16 + rj) * S_O + rq * 16];
        float4 b0 = *(const float4*)&base[0];
        float4 b1 = *(const float4*)&base[4];
        float4 b2 = *(const float4*)&base[8];
        float4 b3 = *(const float4*)&base[12];
        float s = b0.x + b0.y + b0.z + b0.w + b1.x + b1.y + b1.z + b1.w
                + b2.x + b2.y + b2.z + b2.w + b3.x + b3.y + b3.z + b3.w;
        s += __shfl_down(s, 1);
        s += __shfl_down(s, 2);
        if (rq == 0) At[rj][rwv] = s;
    }

    // ---- phase 3: O partials, wave w covers k in [50w, 50w+50) ----
    {
        float4 po[4];
#pragma unroll
        for (int f = 0; f < 4; ++f) po[f] = make_float4(0.f, 0.f, 0.f, 0.f);
#pragma unroll
        for (int kk = 0; kk < 8; ++kk) {
            float4 wv = *(const float4*)&W4[kb + kk][0];
            float4 fv = pf[kk];
            po[0].x += wv.x * fv.x; po[0].y += wv.x * fv.y; po[0].z += wv.x * fv.z; po[0].w += wv.x * fv.w;
            po[1].x += wv.y * fv.x; po[1].y += wv.y * fv.y; po[1].z += wv.y * fv.z; po[1].w += wv.y * fv.w;
            po[2].x += wv.z * fv.x; po[2].y += wv.z * fv.y; po[2].z += wv.z * fv.z; po[2].w += wv.z * fv.w;
            po[3].x += wv.w * fv.x; po[3].y += wv.w * fv.y; po[3].z += wv.w * fv.z; po[3].w += wv.w * fv.w;
        }
#pragma unroll 6
        for (int kk = 8; kk < 50; ++kk) {
            float4 wv = *(const float4*)&W4[kb + kk][0];
            float4 fv = fB4[(size_t)(kb + kk) * 64 + l];
            po[0].x += wv.x * fv.x; po[0].y += wv.x * fv.y; po[0].z += wv.x * fv.z; po[0].w += wv.x * fv.w;
            po[1].x += wv.y * fv.x; po[1].y += wv.y * fv.y; po[1].z += wv.y * fv.z; po[1].w += wv.y * fv.w;
            po[2].x += wv.z * fv.x; po[2].y += wv.z * fv.y; po[2].z += wv.z * fv.z; po[2].w += wv.z * fv.w;
            po[3].x += wv.w * fv.x; po[3].y += wv.w * fv.y; po[3].z += wv.w * fv.z; po[3].w += wv.w * fv.w;
        }
#pragma unroll
        for (int f = 0; f < 4; ++f) {
            upool[(64 + w * 16 + f * 4 + 0) * S_O + l] = po[f].x;
            upool[(64 + w * 16 + f * 4 + 1) * S_O + l] = po[f].y;
            upool[(64 + w * 16 + f * 4 + 2) * S_O + l] = po[f].z;
            upool[(64 + w * 16 + f * 4 + 3) * S_O + l] = po[f].w;
        }
    }
    __syncthreads();   // barrier 2: O-partials + At visible

    // ---- final: thread = d ----
    {
        const int d = tid, l0 = d >> 2, q = d & 3;
        float v0 = 0.f, v1 = 0.f, v2 = 0.f, v3 = 0.f;
#pragma unroll
        for (int ww = 0; ww < 4; ++ww) {
            v0 += upool[(64 + ww * 16 + 0 * 4 + q) * S_O + l0];
            v1 += upool[(64 + ww * 16 + 1 * 4 + q) * S_O + l0];
            v2 += upool[(64 + ww * 16 + 2 * 4 + q) * S_O + l0];
            v3 += upool[(64 + ww * 16 + 3 * 4 + q) * S_O + l0];
        }
        float ab = p2_b[d];
        v0 += ab; v1 += ab; v2 += ab; v3 += ab;
#pragma unroll
        for (int p = 0; p < 16; ++p) {
            float pw = p2_w[p * DIM_ + d];
            float4 av = *(const float4*)&At[p][0];
            v0 += av.x * pw; v1 += av.y * pw; v2 += av.z * pw; v3 += av.w * pw;
        }
        float* op = out + ((size_t)b * T_ + t0) * DIM_ + d;
        op[0 * DIM_] = v0;
        op[1 * DIM_] = v1;
        op[2 * DIM_] = v2;
        op[3 * DIM_] = v3;
    }
}

// ---------------------------------------------------------------------------
extern "C" void kernel_launch(void* const* d_in, const int* in_sizes, int n_in,
                              void* d_out, int out_size, void* d_ws, size_t ws_size,
                              hipStream_t stream) {
    const float* durations = (const float*)d_in[1];
    const float* features  = (const float*)d_in[2];
    const float* conv1_w   = (const float*)d_in[3];
    const float* conv1_b   = (const float*)d_in[4];
    const float* conv2_w   = (const float*)d_in[5];
    const float* conv2_b   = (const float*)d_in[6];
    const float* sw1_w1    = (const float*)d_in[7];
    const float* sw1_b1    = (const float*)d_in[8];
    const float* sw1_w2    = (const float*)d_in[9];
    const float* sw1_b2    = (const float*)d_in[10];
    const float* sw2_w1    = (const float*)d_in[11];
    const float* sw2_b1    = (const float*)d_in[12];
    const float* sw2_w2    = (const float*)d_in[13];
    const float* sw2_b2    = (const float*)d_in[14];
    const float* p1_w      = (const float*)d_in[15];
    const float* p1_b      = (const float*)d_in[16];
    const float* p2_w      = (const float*)d_in[17];
    const float* p2_b      = (const float*)d_in[18];
    float* out = (float*)d_out;

    float* cw = (float*)d_ws;   // [B][18][K]

    prep_kernel<<<dim3(13, B_), 256, 0, stream>>>(
        durations, features, conv1_w, conv1_b, conv2_w, conv2_b,
        sw1_w1, sw1_b1, sw2_w1, sw2_b1, cw);
    main_kernel<<<dim3(T_ / 4, B_), 256, 0, stream>>>(
        features, cw,
        sw1_w1, sw1_w2, sw1_b2,
        sw2_w1, sw2_w2, sw2_b2,
        p1_w, p1_b, p2_w, p2_b, out);
}